// Round 5
// baseline (328.039 us; speedup 1.0000x reference)
//
#include <hip/hip_runtime.h>
#include <cstdint>

typedef unsigned short u16;
typedef uint32_t u32;

typedef __bf16 bf16x8 __attribute__((ext_vector_type(8)));
typedef float  f32x2  __attribute__((ext_vector_type(2)));
typedef float  f32x4  __attribute__((ext_vector_type(4)));
typedef float  f32x16 __attribute__((ext_vector_type(16)));
typedef u16    u16x4  __attribute__((ext_vector_type(4)));
typedef u16    u16x8  __attribute__((ext_vector_type(8)));

__device__ __forceinline__ u16 f2bf(float f) {
    u32 x = __float_as_uint(f);
    return (u16)((x + 0x7FFFu + ((x >> 16) & 1u)) >> 16);
}
__device__ __forceinline__ float lrelu(float x) { return fmaxf(x, 0.1f * x); }

// pack two f32 -> dword of two bf16 (round via +0x8000), lo->low16 hi->high16
__device__ __forceinline__ u32 pack_rn(float lo, float hi) {
    u32 a = __float_as_uint(lo) + 0x8000u;
    u32 b = __float_as_uint(hi) + 0x8000u;
    return __builtin_amdgcn_perm(b, a, 0x07060302u);
}

// ---------------------------------------------------------------------------
// Prep: x -> xb bf16 [b][l][e]; conv_w -> wcb bf16 [c][tap*512+e];
//       W2/3/4+b2/3/4 -> wfrag (MFMA frag-blocked, bias as 9th K-tile);
//       hW[b][d] = h @ W1jh.T (16-lane groups, coalesced)
// wfrag layout (u16): [layer][ks9][h][n][j8]  strides 18432/2048/1024/8/1
// ---------------------------------------------------------------------------
__global__ __launch_bounds__(256) void k_prep(
    const float* __restrict__ x, const float* __restrict__ conv_w,
    const float* __restrict__ W2, const float* __restrict__ W3, const float* __restrict__ W4,
    const float* __restrict__ b2, const float* __restrict__ b3, const float* __restrict__ b4,
    const float* __restrict__ h, const float* __restrict__ W1,
    u16* __restrict__ xb, u16* __restrict__ wcb, u16* __restrict__ wfrag,
    float* __restrict__ hW)
{
    int blk = blockIdx.x, tid = threadIdx.x;
    if (blk < 1280) {                       // xb: 1,310,720 elems, 4/thread
        int o = (blk * 256 + tid) * 4;
        int e = o & 511;
        int bl = o >> 9;
        int b = bl / 160, l = bl % 160;
        f32x4 v = *(const f32x4*)(x + ((size_t)(l * 16 + b)) * 512 + e);
        u16x4 ov;
        ov[0] = f2bf(v[0]); ov[1] = f2bf(v[1]); ov[2] = f2bf(v[2]); ov[3] = f2bf(v[3]);
        *(u16x4*)&xb[o] = ov;
    } else if (blk < 1664) {                // wcb: 393,216 elems
        int o = ((blk - 1280) * 256 + tid) * 4;
        int c = o / 1536, rem = o % 1536;
        int t = rem >> 9, e0 = rem & 511;
        u16x4 ov;
        #pragma unroll
        for (int q = 0; q < 4; q++)
            ov[q] = f2bf(conv_w[((size_t)c * 512 + e0 + q) * 3 + t]);
        *(u16x4*)&wcb[o] = ov;
    } else if (blk < 1718) {                // wfrag: 55,296 elems, 54 blocks
        int o = ((blk - 1664) * 256 + tid) * 4;
        int layer = o / 18432, rem = o % 18432;
        int ks9 = rem >> 11;
        int rem2 = rem & 2047;
        int hh = rem2 >> 10;
        int rem3 = rem2 & 1023;
        int n = rem3 >> 3, j0 = rem3 & 7;   // j0 in {0,4}
        const float* W = (layer == 0) ? W2 : (layer == 1) ? W3 : W4;
        const float* bi = (layer == 0) ? b2 : (layer == 1) ? b3 : b4;
        u16x4 ov;
        if (ks9 < 8) {
            f32x4 v = *(const f32x4*)(W + (size_t)n * 128 + 16 * ks9 + 8 * hh + j0);
            ov[0] = f2bf(v[0]); ov[1] = f2bf(v[1]); ov[2] = f2bf(v[2]); ov[3] = f2bf(v[3]);
        } else {
            ov[0] = (hh == 0 && j0 == 0) ? f2bf(bi[n]) : (u16)0;
            ov[1] = 0; ov[2] = 0; ov[3] = 0;
        }
        *(u16x4*)&wfrag[o] = ov;
    } else {                                // hW: 2048 outs x 16 lanes, 128 blocks
        int gid = (blk - 1718) * 256 + tid;
        int outp = gid >> 4, q = gid & 15;
        int b = outp >> 7, d = outp & 127;
        const float* hr = h + (size_t)b * 512;
        const float* wr = W1 + (size_t)d * 1028 + 516;
        float acc = 0.f;
        #pragma unroll
        for (int c = 0; c < 8; c++) {
            int k = c * 64 + q * 4;
            f32x4 hv = *(const f32x4*)(hr + k);
            f32x4 wv = *(const f32x4*)(wr + k);
            acc += hv[0]*wv[0] + hv[1]*wv[1] + hv[2]*wv[2] + hv[3]*wv[3];
        }
        acc += __shfl_xor(acc, 1); acc += __shfl_xor(acc, 2);
        acc += __shfl_xor(acc, 4); acc += __shfl_xor(acc, 8);
        if (q == 0) hW[outp] = acc;
    }
}

// ---------------------------------------------------------------------------
// Conv1d (K=3, pad 1) as im2col GEMM, bf16 MFMA (unchanged).
// ---------------------------------------------------------------------------
__global__ __launch_bounds__(256, 2) void k_conv(
    const u16* __restrict__ xb, const u16* __restrict__ wcb,
    const float* __restrict__ conv_b,
    float* __restrict__ ws_y, float* __restrict__ stats)
{
    __shared__ u16 xs[34 * 520];
    int tid = threadIdx.x, wg = blockIdx.x;
    int rowtile = wg >> 2, cg = wg & 3;
    int b = rowtile / 5, l0 = (rowtile % 5) * 32;

    for (int t = tid; t < 34 * 64; t += 256) {
        int s = t >> 6, ch = t & 63;
        int lg = l0 + s - 1;
        u16x8 v = {};
        if (lg >= 0 && lg < 160)
            v = *(const u16x8*)(xb + ((size_t)(b * 160 + lg)) * 512 + ch * 8);
        *(u16x8*)&xs[s * 520 + ch * 8] = v;
    }
    __syncthreads();

    int lane = tid & 63, w = tid >> 6;
    int row16 = lane & 15, quad = lane >> 4;
    int c_n = cg * 64 + w * 16 + row16;
    const u16* wrow = wcb + (size_t)c_n * 1536;

    f32x4 acc0 = {0,0,0,0}, acc1 = {0,0,0,0};
    for (int ks4 = 0; ks4 < 48; ks4 += 4) {
        bf16x8 wf[4];
        #pragma unroll
        for (int q = 0; q < 4; q++)
            wf[q] = *(const bf16x8*)(wrow + (ks4 + q) * 32 + quad * 8);
        #pragma unroll
        for (int q = 0; q < 4; q++) {
            int k = (ks4 + q) * 32 + quad * 8;
            int tap = k >> 9, e = k & 511;
            bf16x8 a0 = *(const bf16x8*)&xs[(row16 + tap) * 520 + e];
            bf16x8 a1 = *(const bf16x8*)&xs[(16 + row16 + tap) * 520 + e];
            acc0 = __builtin_amdgcn_mfma_f32_16x16x32_bf16(a0, wf[q], acc0, 0, 0, 0);
            acc1 = __builtin_amdgcn_mfma_f32_16x16x32_bf16(a1, wf[q], acc1, 0, 0, 0);
        }
    }

    float bias = conv_b[c_n];
    float sum = 0.f, sq = 0.f;
    #pragma unroll
    for (int mt = 0; mt < 2; mt++) {
        f32x4 a = mt ? acc1 : acc0;
        #pragma unroll
        for (int r = 0; r < 4; r++) {
            float v = lrelu(a[r] + bias);
            int lr = l0 + mt * 16 + quad * 4 + r;
            ws_y[((size_t)(b * 160 + lr)) * 256 + c_n] = v;
            sum += v; sq += v * v;
        }
    }
    sum += __shfl_xor(sum, 16); sum += __shfl_xor(sum, 32);
    sq  += __shfl_xor(sq, 16);  sq  += __shfl_xor(sq, 32);
    if (quad == 0) {
        atomicAdd(&stats[c_n], sum);
        atomicAdd(&stats[256 + c_n], sq);
    }
}

// ---------------------------------------------------------------------------
// BN + coords -> xf, u/v projections (unchanged).
// ---------------------------------------------------------------------------
__global__ __launch_bounds__(256) void k_uv(
    const float* __restrict__ ws_y, const float* __restrict__ stats,
    const float* __restrict__ bn_g, const float* __restrict__ bn_b,
    const float* __restrict__ W1, const float* __restrict__ b1,
    const float* __restrict__ hW,
    float* __restrict__ uu, float* __restrict__ vv)
{
    __shared__ float a_s[256], c_s[256];
    __shared__ float xfs[8 * 260];
    int tid = threadIdx.x;
    int row0 = blockIdx.x * 8;
    int b = row0 / 160, l0 = row0 % 160;
    {
        int c = tid;
        float mu  = stats[c] * (1.0f / 2560.0f);
        float var = stats[256 + c] * (1.0f / 2560.0f) - mu * mu;
        float rs  = rsqrtf(var + 1e-5f) * bn_g[c];
        a_s[c] = rs;
        c_s[c] = bn_b[c] - mu * rs;
    }
    __syncthreads();
    float sLf = sqrtf(160.0f);
    for (int idx = tid; idx < 8 * 258; idx += 256) {
        int r = idx / 258, c = idx - r * 258;
        int l = l0 + r;
        float v;
        if (c < 256) {
            v = ws_y[((size_t)(b * 160 + l)) * 256 + c] * a_s[c] + c_s[c];
        } else {
            float fi = (float)l;
            if (c == 256) v = (fi / sLf - 2.0f) * 0.5f;
            else { float m = fi - floorf(fi / sLf) * sLf; v = (m - 2.0f) * 0.5f; }
        }
        xfs[r * 260 + c] = v;
    }
    __syncthreads();

    bool isv = tid >= 128;
    int d = tid & 127;
    const float* wrow = W1 + (size_t)d * 1028 + (isv ? 258 : 0);

    float acc[8] = {0,0,0,0,0,0,0,0};
    for (int c0 = 0; c0 < 256; c0 += 32) {
        f32x4 wv[8];
        #pragma unroll
        for (int q = 0; q < 8; q++)
            wv[q] = *(const f32x4*)(wrow + c0 + q * 4);
        #pragma unroll
        for (int q = 0; q < 8; q++) {
            #pragma unroll
            for (int r = 0; r < 8; r++) {
                f32x4 xv = *(const f32x4*)&xfs[r * 260 + c0 + q * 4];
                acc[r] += wv[q][0]*xv[0] + wv[q][1]*xv[1] + wv[q][2]*xv[2] + wv[q][3]*xv[3];
            }
        }
    }
    float w256 = wrow[256], w257 = wrow[257];
    #pragma unroll
    for (int r = 0; r < 8; r++)
        acc[r] += xfs[r * 260 + 256] * w256 + xfs[r * 260 + 257] * w257;

    float vadd = isv ? (hW[b * 128 + d] + b1[d]) : 0.f;
    float* dst = isv ? vv : uu;
    #pragma unroll
    for (int r = 0; r < 8; r++)
        dst[((size_t)(b * 160 + l0 + r)) * 128 + d] = acc[r] + vadd;
}

// ---------------------------------------------------------------------------
// Fused pairwise MLP v4 — z in registers, T=2, NO sacc array.
// Layers 0,1: D = W(A) x z^T(B)  -> C-layout cols=m, in-register transition
//             to next-layer z-frags (lane-preserving: C col = B col = m).
// Layer 2   : FLIPPED: D = z(A) x W(B) -> pairs m land in REGS, features n on
//             lanes; pair-sum = 16 in-lane adds + shfl_xor(32). ssum[4] regs.
// Bias via 9th K-tile (const-1 frag on the z side, bias frag on the W side).
// Weights one layer at a time in LDS (36.9KB); same wfrag layout serves both
// A-use and B-use (MFMA A and B physical layouts are identical).
// Grid: 800 WGs = 16 b x 50; WG = 16 tiles (2 sc x 4 waves x 2 slots).
// ---------------------------------------------------------------------------
__global__ __launch_bounds__(256, 2) void k_mlp(
    const float* __restrict__ vv, const float* __restrict__ uu,
    const u16* __restrict__ wfrag,
    float* __restrict__ s_glob)
{
    __shared__ __align__(16) u16 Wlds[18432];   // [ks9][h][n][8]
    __shared__ float spart[128];
    int tid = threadIdx.x;
    int wave = tid >> 6, lane = tid & 63;
    int h = lane >> 5, lo = lane & 31;
    int b = blockIdx.x / 50, sub = blockIdx.x % 50;

    if (tid < 128) spart[tid] = 0.f;

    u32 selv = h ? 0x07060302u : 0x05040100u;
    uint4 biasfrag;
    biasfrag.x = (h == 0) ? 0x00003F80u : 0u;   // bf16 1.0 at j=0, h=0
    biasfrag.y = 0u; biasfrag.z = 0u; biasfrag.w = 0u;

    f32x16 Z;
    #pragma unroll
    for (int r = 0; r < 16; r++) Z[r] = 0.f;

    uint4 B[2][8];              // per-slot z-frags (bf16 packed)
    float ssum[4] = {0.f, 0.f, 0.f, 0.f};

    for (int sc = 0; sc < 2; sc++) {
        for (int layer = 0; layer < 3; layer++) {
            __syncthreads();                    // prior readers done
            {   // stage this layer's weights: 2304 x 16B
                const uint4* src = (const uint4*)(wfrag + layer * 18432);
                #pragma unroll
                for (int it = 0; it < 9; it++) {
                    int idx = it * 256 + tid;
                    *(uint4*)&Wlds[idx * 8] = src[idx];
                }
            }
            __syncthreads();                    // weights visible

            #pragma unroll
            for (int slot = 0; slot < 2; slot++) {
                int tileb = sub * 16 + sc * 8 + wave * 2 + slot;

                if (layer == 0) {
                    // build z0 frags: z0[m=lo][k] = lrelu(v_i + u_j)
                    int i  = (tileb / 10) * 2  + (lo >> 4);
                    int jj = (tileb % 10) * 16 + (lo & 15);
                    const float* vr = vv + ((size_t)(b * 160 + i))  * 128 + 8 * h;
                    const float* ur = uu + ((size_t)(b * 160 + jj)) * 128 + 8 * h;
                    #pragma unroll
                    for (int ks = 0; ks < 8; ks++) {
                        f32x4 v0 = *(const f32x4*)(vr + 16 * ks);
                        f32x4 v1 = *(const f32x4*)(vr + 16 * ks + 4);
                        f32x4 u0 = *(const f32x4*)(ur + 16 * ks);
                        f32x4 u1 = *(const f32x4*)(ur + 16 * ks + 4);
                        uint4 d;
                        d.x = pack_rn(lrelu(v0[0]+u0[0]), lrelu(v0[1]+u0[1]));
                        d.y = pack_rn(lrelu(v0[2]+u0[2]), lrelu(v0[3]+u0[3]));
                        d.z = pack_rn(lrelu(v1[0]+u1[0]), lrelu(v1[1]+u1[1]));
                        d.w = pack_rn(lrelu(v1[2]+u1[2]), lrelu(v1[3]+u1[3]));
                        B[slot][ks] = d;
                    }
                }

                f32x16 acc[4];
                #pragma unroll
                for (int nt = 0; nt < 4; nt++) {
                    f32x16 a;
                    #pragma unroll
                    for (int ks = 0; ks < 9; ks++) {
                        bf16x8 wf = *(const bf16x8*)&Wlds[(size_t)(ks * 256 + h * 128 + nt * 32 + lo) * 8];
                        uint4 zu = (ks < 8) ? B[slot][ks] : biasfrag;
                        bf16x8 zf = *(bf16x8*)&zu;
                        if (layer < 2)
                            a = __builtin_amdgcn_mfma_f32_32x32x16_bf16(wf, zf, ks ? a : Z, 0, 0, 0);
                        else
                            a = __builtin_amdgcn_mfma_f32_32x32x16_bf16(zf, wf, ks ? a : Z, 0, 0, 0);
                    }
                    acc[nt] = a;
                }

                if (layer < 2) {
                    // C-layout -> z-frag layout, in-register (lane-preserving)
                    #pragma unroll
                    for (int nt = 0; nt < 4; nt++) {
                        u32 pk[4][2];
                        #pragma unroll
                        for (int c = 0; c < 4; c++)
                            #pragma unroll
                            for (int p = 0; p < 2; p++)
                                pk[c][p] = pack_rn(lrelu(acc[nt][c + 8*p]),
                                                   lrelu(acc[nt][c + 4 + 8*p]));
                        u32 sh[2][4][2];
                        #pragma unroll
                        for (int g = 0; g < 2; g++)
                            #pragma unroll
                            for (int c = 0; c < 4; c++)
                                #pragma unroll
                                for (int p = 0; p < 2; p++)
                                    sh[g][c][p] = (u32)__shfl((int)pk[c][p], g * 32 + lo, 64);
                        #pragma unroll
                        for (int p = 0; p < 2; p++) {
                            uint4 d;
                            d.x = __builtin_amdgcn_perm(sh[0][1][p], sh[0][0][p], selv);
                            d.y = __builtin_amdgcn_perm(sh[0][3][p], sh[0][2][p], selv);
                            d.z = __builtin_amdgcn_perm(sh[1][1][p], sh[1][0][p], selv);
                            d.w = __builtin_amdgcn_perm(sh[1][3][p], sh[1][2][p], selv);
                            B[slot][2 * nt + p] = d;
                        }
                    }
                } else {
                    // final layer: pairs m are in regs -> in-lane sum
                    #pragma unroll
                    for (int nt = 0; nt < 4; nt++) {
                        float t = 0.f;
                        #pragma unroll
                        for (int r = 0; r < 16; r++)
                            t += lrelu(acc[nt][r]);
                        ssum[nt] += t;
                    }
                }
            }
        }
    }

    // combine h-halves (m 0..31) and flush: lane lo owns feature n = nt*32+lo
    #pragma unroll
    for (int nt = 0; nt < 4; nt++) {
        float v = ssum[nt] + __shfl_xor(ssum[nt], 32);
        if (h == 0) atomicAdd(&spart[nt * 32 + lo], v);
    }
    __syncthreads();
    if (tid < 128) atomicAdd(&s_glob[b * 128 + tid], spart[tid]);
}

// ---------------------------------------------------------------------------
// Final: s -> lrelu(W5) -> lrelu(W6) -> out. One WG (256 thr, 4 waves) per
// batch, wave-per-output coalesced row reductions.
// ---------------------------------------------------------------------------
__global__ __launch_bounds__(256) void k_final(
    const float* __restrict__ s_glob,
    const float* __restrict__ W5, const float* __restrict__ b5,
    const float* __restrict__ W6, const float* __restrict__ b6,
    float* __restrict__ out)
{
    __shared__ float sh[128], t5[128];
    int b = blockIdx.x, tid = threadIdx.x;
    int wave = tid >> 6, lane = tid & 63;
    if (tid < 128) sh[tid] = s_glob[b * 128 + tid];
    __syncthreads();
    f32x2 shv = *(const f32x2*)&sh[lane * 2];
    #pragma unroll 4
    for (int it = 0; it < 32; it++) {
        int d = wave * 32 + it;
        f32x2 wv = *(const f32x2*)(W5 + (size_t)d * 128 + lane * 2);
        float v = shv[0] * wv[0] + shv[1] * wv[1];
        v += __shfl_xor(v, 1);  v += __shfl_xor(v, 2);  v += __shfl_xor(v, 4);
        v += __shfl_xor(v, 8);  v += __shfl_xor(v, 16); v += __shfl_xor(v, 32);
        if (lane == 0) t5[d] = lrelu(v + b5[d]);
    }
    __syncthreads();
    f32x2 tv = *(const f32x2*)&t5[lane * 2];
    #pragma unroll 4
    for (int it = 0; it < 128; it++) {
        int o = wave * 128 + it;
        f32x2 wv = *(const f32x2*)(W6 + (size_t)o * 128 + lane * 2);
        float v = tv[0] * wv[0] + tv[1] * wv[1];
        v += __shfl_xor(v, 1);  v += __shfl_xor(v, 2);  v += __shfl_xor(v, 4);
        v += __shfl_xor(v, 8);  v += __shfl_xor(v, 16); v += __shfl_xor(v, 32);
        if (lane == 0) out[b * 512 + o] = lrelu(v + b6[o]);
    }
}

// ---------------------------------------------------------------------------
extern "C" void kernel_launch(void* const* d_in, const int* in_sizes, int n_in,
                              void* d_out, int out_size, void* d_ws, size_t ws_size,
                              hipStream_t stream)
{
    const float* x      = (const float*)d_in[0];
    const float* h      = (const float*)d_in[1];
    const float* conv_w = (const float*)d_in[2];
    const float* conv_b = (const float*)d_in[3];
    const float* bn_g   = (const float*)d_in[4];
    const float* bn_b   = (const float*)d_in[5];
    const float* W1     = (const float*)d_in[6];
    const float* b1     = (const float*)d_in[7];
    const float* W2     = (const float*)d_in[8];
    const float* b2     = (const float*)d_in[9];
    const float* W3     = (const float*)d_in[10];
    const float* b3     = (const float*)d_in[11];
    const float* W4     = (const float*)d_in[12];
    const float* b4     = (const float*)d_in[13];
    const float* W5     = (const float*)d_in[14];
    const float* b5     = (const float*)d_in[15];
    const float* W6     = (const float*)d_in[16];
    const float* b6     = (const float*)d_in[17];

    char* ws = (char*)d_ws;
    float* s_glob = (float*)(ws + 0);          //  8 KB
    float* stats  = (float*)(ws + 8192);       //  2 KB
    float* hW     = (float*)(ws + 10240);      //  8 KB
    float* ws_y   = (float*)(ws + 18432);      //  2.62 MB
    float* vv     = (float*)(ws + 2639872);    //  1.31 MB
    float* uu     = (float*)(ws + 3950592);    //  1.31 MB
    u16*   xb     = (u16*)  (ws + 5261312);    //  2.62 MB
    u16*   wcb    = (u16*)  (ws + 7882752);    //  786 KB
    u16*   wfrag  = (u16*)  (ws + 8669184);    //  110.6 KB (end 8,779,776)

    hipMemsetAsync(ws, 0, 10240, stream);      // zero s_glob + stats
    k_prep <<<1846, 256, 0, stream>>>(x, conv_w, W2, W3, W4, b2, b3, b4, h, W1,
                                      xb, wcb, wfrag, hW);
    k_conv <<<320, 256, 0, stream>>>(xb, wcb, conv_b, ws_y, stats);
    k_uv   <<<320, 256, 0, stream>>>(ws_y, stats, bn_g, bn_b, W1, b1, hW, uu, vv);
    k_mlp  <<<800, 256, 0, stream>>>(vv, uu, wfrag, s_glob);
    k_final<<<16, 256, 0, stream>>>(s_glob, W5, b5, W6, b6, (float*)d_out);
}

// Round 6
// 209.485 us; speedup vs baseline: 1.5659x; 1.5659x over previous
//
#include <hip/hip_runtime.h>
#include <cstdint>

typedef unsigned short u16;
typedef uint32_t u32;

typedef __bf16 bf16x8 __attribute__((ext_vector_type(8)));
typedef float  f32x2  __attribute__((ext_vector_type(2)));
typedef float  f32x4  __attribute__((ext_vector_type(4)));
typedef float  f32x16 __attribute__((ext_vector_type(16)));
typedef u16    u16x4  __attribute__((ext_vector_type(4)));
typedef u16    u16x8  __attribute__((ext_vector_type(8)));

__device__ __forceinline__ u16 f2bf(float f) {
    u32 x = __float_as_uint(f);
    return (u16)((x + 0x7FFFu + ((x >> 16) & 1u)) >> 16);
}
__device__ __forceinline__ float lrelu(float x) { return fmaxf(x, 0.1f * x); }

// pack two f32 -> dword of two bf16 (round via +0x8000), lo->low16 hi->high16
__device__ __forceinline__ u32 pack_rn(float lo, float hi) {
    u32 a = __float_as_uint(lo) + 0x8000u;
    u32 b = __float_as_uint(hi) + 0x8000u;
    return __builtin_amdgcn_perm(b, a, 0x07060302u);
}

// ---------------------------------------------------------------------------
// Prep: x -> xb bf16 [b][l][e]; conv_w -> wcb bf16 [c][tap*512+e];
//       W2/3/4+b2/3/4 -> wfrag (MFMA frag-blocked, bias as 9th K-tile);
//       hW[b][d] = h @ W1jh.T (16-lane groups, coalesced)
// wfrag layout (u16): [layer][ks9][h][n][j8]  strides 18432/2048/1024/8/1
// ---------------------------------------------------------------------------
__global__ __launch_bounds__(256) void k_prep(
    const float* __restrict__ x, const float* __restrict__ conv_w,
    const float* __restrict__ W2, const float* __restrict__ W3, const float* __restrict__ W4,
    const float* __restrict__ b2, const float* __restrict__ b3, const float* __restrict__ b4,
    const float* __restrict__ h, const float* __restrict__ W1,
    u16* __restrict__ xb, u16* __restrict__ wcb, u16* __restrict__ wfrag,
    float* __restrict__ hW)
{
    int blk = blockIdx.x, tid = threadIdx.x;
    if (blk < 1280) {                       // xb: 1,310,720 elems, 4/thread
        int o = (blk * 256 + tid) * 4;
        int e = o & 511;
        int bl = o >> 9;
        int b = bl / 160, l = bl % 160;
        f32x4 v = *(const f32x4*)(x + ((size_t)(l * 16 + b)) * 512 + e);
        u16x4 ov;
        ov[0] = f2bf(v[0]); ov[1] = f2bf(v[1]); ov[2] = f2bf(v[2]); ov[3] = f2bf(v[3]);
        *(u16x4*)&xb[o] = ov;
    } else if (blk < 1664) {                // wcb: 393,216 elems
        int o = ((blk - 1280) * 256 + tid) * 4;
        int c = o / 1536, rem = o % 1536;
        int t = rem >> 9, e0 = rem & 511;
        u16x4 ov;
        #pragma unroll
        for (int q = 0; q < 4; q++)
            ov[q] = f2bf(conv_w[((size_t)c * 512 + e0 + q) * 3 + t]);
        *(u16x4*)&wcb[o] = ov;
    } else if (blk < 1718) {                // wfrag: 55,296 elems, 54 blocks
        int o = ((blk - 1664) * 256 + tid) * 4;
        int layer = o / 18432, rem = o % 18432;
        int ks9 = rem >> 11;
        int rem2 = rem & 2047;
        int hh = rem2 >> 10;
        int rem3 = rem2 & 1023;
        int n = rem3 >> 3, j0 = rem3 & 7;   // j0 in {0,4}
        const float* W = (layer == 0) ? W2 : (layer == 1) ? W3 : W4;
        const float* bi = (layer == 0) ? b2 : (layer == 1) ? b3 : b4;
        u16x4 ov;
        if (ks9 < 8) {
            f32x4 v = *(const f32x4*)(W + (size_t)n * 128 + 16 * ks9 + 8 * hh + j0);
            ov[0] = f2bf(v[0]); ov[1] = f2bf(v[1]); ov[2] = f2bf(v[2]); ov[3] = f2bf(v[3]);
        } else {
            ov[0] = (hh == 0 && j0 == 0) ? f2bf(bi[n]) : (u16)0;
            ov[1] = 0; ov[2] = 0; ov[3] = 0;
        }
        *(u16x4*)&wfrag[o] = ov;
    } else {                                // hW: 2048 outs x 16 lanes, 128 blocks
        int gid = (blk - 1718) * 256 + tid;
        int outp = gid >> 4, q = gid & 15;
        int b = outp >> 7, d = outp & 127;
        const float* hr = h + (size_t)b * 512;
        const float* wr = W1 + (size_t)d * 1028 + 516;
        float acc = 0.f;
        #pragma unroll
        for (int c = 0; c < 8; c++) {
            int k = c * 64 + q * 4;
            f32x4 hv = *(const f32x4*)(hr + k);
            f32x4 wv = *(const f32x4*)(wr + k);
            acc += hv[0]*wv[0] + hv[1]*wv[1] + hv[2]*wv[2] + hv[3]*wv[3];
        }
        acc += __shfl_xor(acc, 1); acc += __shfl_xor(acc, 2);
        acc += __shfl_xor(acc, 4); acc += __shfl_xor(acc, 8);
        if (q == 0) hW[outp] = acc;
    }
}

// ---------------------------------------------------------------------------
// Conv1d (K=3, pad 1) as im2col GEMM, bf16 MFMA (unchanged).
// ---------------------------------------------------------------------------
__global__ __launch_bounds__(256, 2) void k_conv(
    const u16* __restrict__ xb, const u16* __restrict__ wcb,
    const float* __restrict__ conv_b,
    float* __restrict__ ws_y, float* __restrict__ stats)
{
    __shared__ u16 xs[34 * 520];
    int tid = threadIdx.x, wg = blockIdx.x;
    int rowtile = wg >> 2, cg = wg & 3;
    int b = rowtile / 5, l0 = (rowtile % 5) * 32;

    for (int t = tid; t < 34 * 64; t += 256) {
        int s = t >> 6, ch = t & 63;
        int lg = l0 + s - 1;
        u16x8 v = {};
        if (lg >= 0 && lg < 160)
            v = *(const u16x8*)(xb + ((size_t)(b * 160 + lg)) * 512 + ch * 8);
        *(u16x8*)&xs[s * 520 + ch * 8] = v;
    }
    __syncthreads();

    int lane = tid & 63, w = tid >> 6;
    int row16 = lane & 15, quad = lane >> 4;
    int c_n = cg * 64 + w * 16 + row16;
    const u16* wrow = wcb + (size_t)c_n * 1536;

    f32x4 acc0 = {0,0,0,0}, acc1 = {0,0,0,0};
    for (int ks4 = 0; ks4 < 48; ks4 += 4) {
        bf16x8 wf[4];
        #pragma unroll
        for (int q = 0; q < 4; q++)
            wf[q] = *(const bf16x8*)(wrow + (ks4 + q) * 32 + quad * 8);
        #pragma unroll
        for (int q = 0; q < 4; q++) {
            int k = (ks4 + q) * 32 + quad * 8;
            int tap = k >> 9, e = k & 511;
            bf16x8 a0 = *(const bf16x8*)&xs[(row16 + tap) * 520 + e];
            bf16x8 a1 = *(const bf16x8*)&xs[(16 + row16 + tap) * 520 + e];
            acc0 = __builtin_amdgcn_mfma_f32_16x16x32_bf16(a0, wf[q], acc0, 0, 0, 0);
            acc1 = __builtin_amdgcn_mfma_f32_16x16x32_bf16(a1, wf[q], acc1, 0, 0, 0);
        }
    }

    float bias = conv_b[c_n];
    float sum = 0.f, sq = 0.f;
    #pragma unroll
    for (int mt = 0; mt < 2; mt++) {
        f32x4 a = mt ? acc1 : acc0;
        #pragma unroll
        for (int r = 0; r < 4; r++) {
            float v = lrelu(a[r] + bias);
            int lr = l0 + mt * 16 + quad * 4 + r;
            ws_y[((size_t)(b * 160 + lr)) * 256 + c_n] = v;
            sum += v; sq += v * v;
        }
    }
    sum += __shfl_xor(sum, 16); sum += __shfl_xor(sum, 32);
    sq  += __shfl_xor(sq, 16);  sq  += __shfl_xor(sq, 32);
    if (quad == 0) {
        atomicAdd(&stats[c_n], sum);
        atomicAdd(&stats[256 + c_n], sq);
    }
}

// ---------------------------------------------------------------------------
// BN + coords -> xf, u/v projections (unchanged).
// ---------------------------------------------------------------------------
__global__ __launch_bounds__(256) void k_uv(
    const float* __restrict__ ws_y, const float* __restrict__ stats,
    const float* __restrict__ bn_g, const float* __restrict__ bn_b,
    const float* __restrict__ W1, const float* __restrict__ b1,
    const float* __restrict__ hW,
    float* __restrict__ uu, float* __restrict__ vv)
{
    __shared__ float a_s[256], c_s[256];
    __shared__ float xfs[8 * 260];
    int tid = threadIdx.x;
    int row0 = blockIdx.x * 8;
    int b = row0 / 160, l0 = row0 % 160;
    {
        int c = tid;
        float mu  = stats[c] * (1.0f / 2560.0f);
        float var = stats[256 + c] * (1.0f / 2560.0f) - mu * mu;
        float rs  = rsqrtf(var + 1e-5f) * bn_g[c];
        a_s[c] = rs;
        c_s[c] = bn_b[c] - mu * rs;
    }
    __syncthreads();
    float sLf = sqrtf(160.0f);
    for (int idx = tid; idx < 8 * 258; idx += 256) {
        int r = idx / 258, c = idx - r * 258;
        int l = l0 + r;
        float v;
        if (c < 256) {
            v = ws_y[((size_t)(b * 160 + l)) * 256 + c] * a_s[c] + c_s[c];
        } else {
            float fi = (float)l;
            if (c == 256) v = (fi / sLf - 2.0f) * 0.5f;
            else { float m = fi - floorf(fi / sLf) * sLf; v = (m - 2.0f) * 0.5f; }
        }
        xfs[r * 260 + c] = v;
    }
    __syncthreads();

    bool isv = tid >= 128;
    int d = tid & 127;
    const float* wrow = W1 + (size_t)d * 1028 + (isv ? 258 : 0);

    float acc[8] = {0,0,0,0,0,0,0,0};
    for (int c0 = 0; c0 < 256; c0 += 32) {
        f32x4 wv[8];
        #pragma unroll
        for (int q = 0; q < 8; q++)
            wv[q] = *(const f32x4*)(wrow + c0 + q * 4);
        #pragma unroll
        for (int q = 0; q < 8; q++) {
            #pragma unroll
            for (int r = 0; r < 8; r++) {
                f32x4 xv = *(const f32x4*)&xfs[r * 260 + c0 + q * 4];
                acc[r] += wv[q][0]*xv[0] + wv[q][1]*xv[1] + wv[q][2]*xv[2] + wv[q][3]*xv[3];
            }
        }
    }
    float w256 = wrow[256], w257 = wrow[257];
    #pragma unroll
    for (int r = 0; r < 8; r++)
        acc[r] += xfs[r * 260 + 256] * w256 + xfs[r * 260 + 257] * w257;

    float vadd = isv ? (hW[b * 128 + d] + b1[d]) : 0.f;
    float* dst = isv ? vv : uu;
    #pragma unroll
    for (int r = 0; r < 8; r++)
        dst[((size_t)(b * 160 + l0 + r)) * 128 + d] = acc[r] + vadd;
}

// ---------------------------------------------------------------------------
// Fused pairwise MLP v5 — T=1 (one 32-pair tile per wave), per-nt acc
// lifetime (chain -> transition -> free), spill-free at 128 VGPR,
// 4 waves/SIMD (__launch_bounds__(256,4)), 4 WG/CU by LDS (37 KB).
// Layers 0,1: D = W(A) x z^T(B); in-register C->B transition per nt.
// Layer 2:    D = z(A) x W(B); pairs in regs, in-lane sum. Bias = 9th K-tile.
// Grid: 3200 WGs = 16 b x 200 sub; tile = sub*4 + wave (800 tiles/b).
// ---------------------------------------------------------------------------
__global__ __launch_bounds__(256, 4) void k_mlp(
    const float* __restrict__ vv, const float* __restrict__ uu,
    const u16* __restrict__ wfrag,
    float* __restrict__ s_glob)
{
    __shared__ __align__(16) u16 Wlds[18432];   // [ks9][h][n][8]
    __shared__ float spart[128];
    int tid = threadIdx.x;
    int wave = tid >> 6, lane = tid & 63;
    int h = lane >> 5, lo = lane & 31;
    int b = blockIdx.x / 200, sub = blockIdx.x % 200;
    int tileb = sub * 4 + wave;

    if (tid < 128) spart[tid] = 0.f;

    u32 selv = h ? 0x07060302u : 0x05040100u;
    uint4 biasfrag;
    biasfrag.x = (h == 0) ? 0x00003F80u : 0u;   // bf16 1.0 at j=0, h=0
    biasfrag.y = 0u; biasfrag.z = 0u; biasfrag.w = 0u;

    f32x16 Z;
    #pragma unroll
    for (int r = 0; r < 16; r++) Z[r] = 0.f;

    uint4 B[8], Bn[8];          // z-frags (bf16 packed), current/next
    float ssum[4];

    int i  = (tileb / 10) * 2  + (lo >> 4);
    int jj = (tileb % 10) * 16 + (lo & 15);
    const float* vr = vv + ((size_t)(b * 160 + i))  * 128 + 8 * h;
    const float* ur = uu + ((size_t)(b * 160 + jj)) * 128 + 8 * h;

    for (int layer = 0; layer < 3; layer++) {
        __syncthreads();                    // prior readers done
        {   // stage this layer's weights: 2304 x 16B
            const uint4* src = (const uint4*)(wfrag + layer * 18432);
            #pragma unroll
            for (int it = 0; it < 9; it++) {
                int idx = it * 256 + tid;
                *(uint4*)&Wlds[idx * 8] = src[idx];
            }
        }
        __syncthreads();                    // weights visible

        if (layer == 0) {
            // build z0 frags: z0[m=lo][k] = lrelu(v_i + u_j)
            #pragma unroll
            for (int ks = 0; ks < 8; ks++) {
                f32x4 v0 = *(const f32x4*)(vr + 16 * ks);
                f32x4 v1 = *(const f32x4*)(vr + 16 * ks + 4);
                f32x4 u0 = *(const f32x4*)(ur + 16 * ks);
                f32x4 u1 = *(const f32x4*)(ur + 16 * ks + 4);
                uint4 d;
                d.x = pack_rn(lrelu(v0[0]+u0[0]), lrelu(v0[1]+u0[1]));
                d.y = pack_rn(lrelu(v0[2]+u0[2]), lrelu(v0[3]+u0[3]));
                d.z = pack_rn(lrelu(v1[0]+u1[0]), lrelu(v1[1]+u1[1]));
                d.w = pack_rn(lrelu(v1[2]+u1[2]), lrelu(v1[3]+u1[3]));
                B[ks] = d;
            }
        }

        #pragma unroll
        for (int nt = 0; nt < 4; nt++) {
            f32x16 a;
            #pragma unroll
            for (int ks = 0; ks < 9; ks++) {
                bf16x8 wf = *(const bf16x8*)&Wlds[(size_t)(ks * 256 + h * 128 + nt * 32 + lo) * 8];
                uint4 zu = (ks < 8) ? B[ks] : biasfrag;
                bf16x8 zf = *(bf16x8*)&zu;
                if (layer < 2)
                    a = __builtin_amdgcn_mfma_f32_32x32x16_bf16(wf, zf, ks ? a : Z, 0, 0, 0);
                else
                    a = __builtin_amdgcn_mfma_f32_32x32x16_bf16(zf, wf, ks ? a : Z, 0, 0, 0);
            }

            if (layer < 2) {
                // C-layout -> z-frag layout, in-register (per-nt local)
                u32 pk[4][2];
                #pragma unroll
                for (int c = 0; c < 4; c++)
                    #pragma unroll
                    for (int p = 0; p < 2; p++)
                        pk[c][p] = pack_rn(lrelu(a[c + 8*p]),
                                           lrelu(a[c + 4 + 8*p]));
                u32 sh[2][4][2];
                #pragma unroll
                for (int g = 0; g < 2; g++)
                    #pragma unroll
                    for (int c = 0; c < 4; c++)
                        #pragma unroll
                        for (int p = 0; p < 2; p++)
                            sh[g][c][p] = (u32)__shfl((int)pk[c][p], g * 32 + lo, 64);
                #pragma unroll
                for (int p = 0; p < 2; p++) {
                    uint4 d;
                    d.x = __builtin_amdgcn_perm(sh[0][1][p], sh[0][0][p], selv);
                    d.y = __builtin_amdgcn_perm(sh[0][3][p], sh[0][2][p], selv);
                    d.z = __builtin_amdgcn_perm(sh[1][1][p], sh[1][0][p], selv);
                    d.w = __builtin_amdgcn_perm(sh[1][3][p], sh[1][2][p], selv);
                    Bn[2 * nt + p] = d;
                }
            } else {
                float t = 0.f;
                #pragma unroll
                for (int r = 0; r < 16; r++)
                    t += lrelu(a[r]);
                ssum[nt] = t;
            }
        }

        if (layer < 2) {
            #pragma unroll
            for (int ks = 0; ks < 8; ks++) B[ks] = Bn[ks];
        }
    }

    // combine h-halves (m 0..31) and flush: lane lo owns feature n = nt*32+lo
    #pragma unroll
    for (int nt = 0; nt < 4; nt++) {
        float v = ssum[nt] + __shfl_xor(ssum[nt], 32);
        if (h == 0) atomicAdd(&spart[nt * 32 + lo], v);
    }
    __syncthreads();
    if (tid < 128) atomicAdd(&s_glob[b * 128 + tid], spart[tid]);
}

// ---------------------------------------------------------------------------
// Final: s -> lrelu(W5) -> lrelu(W6) -> out. One WG (256 thr) per batch,
// thread-per-output dot products (W rows are L2-hot; no dependent shuffles).
// ---------------------------------------------------------------------------
__global__ __launch_bounds__(256) void k_final(
    const float* __restrict__ s_glob,
    const float* __restrict__ W5, const float* __restrict__ b5,
    const float* __restrict__ W6, const float* __restrict__ b6,
    float* __restrict__ out)
{
    __shared__ float sh[128], t5[128];
    int b = blockIdx.x, tid = threadIdx.x;
    if (tid < 128) sh[tid] = s_glob[b * 128 + tid];
    __syncthreads();
    if (tid < 128) {
        const float* wr = W5 + (size_t)tid * 128;
        float acc = b5[tid];
        #pragma unroll
        for (int k = 0; k < 128; k += 4) {
            f32x4 wv = *(const f32x4*)(wr + k);
            f32x4 sv = *(const f32x4*)&sh[k];
            acc += wv[0]*sv[0] + wv[1]*sv[1] + wv[2]*sv[2] + wv[3]*sv[3];
        }
        t5[tid] = lrelu(acc);
    }
    __syncthreads();
    #pragma unroll
    for (int q = 0; q < 2; q++) {
        int o = q * 256 + tid;
        const float* wr = W6 + (size_t)o * 128;
        float acc = b6[o];
        #pragma unroll
        for (int k = 0; k < 128; k += 4) {
            f32x4 wv = *(const f32x4*)(wr + k);
            f32x4 tv = *(const f32x4*)&t5[k];
            acc += wv[0]*tv[0] + wv[1]*tv[1] + wv[2]*tv[2] + wv[3]*tv[3];
        }
        out[b * 512 + o] = lrelu(acc);
    }
}

// ---------------------------------------------------------------------------
extern "C" void kernel_launch(void* const* d_in, const int* in_sizes, int n_in,
                              void* d_out, int out_size, void* d_ws, size_t ws_size,
                              hipStream_t stream)
{
    const float* x      = (const float*)d_in[0];
    const float* h      = (const float*)d_in[1];
    const float* conv_w = (const float*)d_in[2];
    const float* conv_b = (const float*)d_in[3];
    const float* bn_g   = (const float*)d_in[4];
    const float* bn_b   = (const float*)d_in[5];
    const float* W1     = (const float*)d_in[6];
    const float* b1     = (const float*)d_in[7];
    const float* W2     = (const float*)d_in[8];
    const float* b2     = (const float*)d_in[9];
    const float* W3     = (const float*)d_in[10];
    const float* b3     = (const float*)d_in[11];
    const float* W4     = (const float*)d_in[12];
    const float* b4     = (const float*)d_in[13];
    const float* W5     = (const float*)d_in[14];
    const float* b5     = (const float*)d_in[15];
    const float* W6     = (const float*)d_in[16];
    const float* b6     = (const float*)d_in[17];

    char* ws = (char*)d_ws;
    float* s_glob = (float*)(ws + 0);          //  8 KB
    float* stats  = (float*)(ws + 8192);       //  2 KB
    float* hW     = (float*)(ws + 10240);      //  8 KB
    float* ws_y   = (float*)(ws + 18432);      //  2.62 MB
    float* vv     = (float*)(ws + 2639872);    //  1.31 MB
    float* uu     = (float*)(ws + 3950592);    //  1.31 MB
    u16*   xb     = (u16*)  (ws + 5261312);    //  2.62 MB
    u16*   wcb    = (u16*)  (ws + 7882752);    //  786 KB
    u16*   wfrag  = (u16*)  (ws + 8669184);    //  110.6 KB (end 8,779,776)

    hipMemsetAsync(ws, 0, 10240, stream);      // zero s_glob + stats
    k_prep <<<1846, 256, 0, stream>>>(x, conv_w, W2, W3, W4, b2, b3, b4, h, W1,
                                      xb, wcb, wfrag, hW);
    k_conv <<<320, 256, 0, stream>>>(xb, wcb, conv_b, ws_y, stats);
    k_uv   <<<320, 256, 0, stream>>>(ws_y, stats, bn_g, bn_b, W1, b1, hW, uu, vv);
    k_mlp  <<<3200, 256, 0, stream>>>(vv, uu, wfrag, s_glob);
    k_final<<<16, 256, 0, stream>>>(s_glob, W5, b5, W6, b6, (float*)d_out);
}